// Round 1
// baseline (962.488 us; speedup 1.0000x reference)
//
#include <hip/hip_runtime.h>

// LSTM: SEQ=4096, BATCH=4096, IN=2, HID=8, fp32.
// R7 = occupancy doubling: 32 lanes/batch (was 16) -> 2048 waves = 2/SIMD.
//  - lane = g*8+u within each 32-lane half-wave (g=gate, u=unit); 2 batches/wave
//  - matvec: systolic Gray-code h-rotation (u ^ 0,1,3,2,5,4,6,7), each hop a
//    single DPP (^1=quad_perm, ^2=quad_perm, ^7=row_half_mirror); two fma chains
//  - gate exchange: 4 ds_bpermute (DS pipe, addresses precomputed) instead of
//    10 DPP broadcasts; lane->gate mapping baked into the byte address
//  - c/h updated redundantly in all 32 lanes -> h naturally replicated for the
//    next step's gather; main loop is fully convergent (no exec masking)
//  - numerics identical to R6: weights pre-scaled by -log2e (-2log2e for g~),
//    c kept in scaled space c' = -2*log2e*c, sigmoid/tanh via exp2+rcp only

#define SEQ   4096
#define BATCH 4096
#define PF    8

#define DPP_X1   0xB1  // quad_perm [1,0,3,2] : lane ^ 1
#define DPP_X2   0x4E  // quad_perm [2,3,0,1] : lane ^ 2
#define DPP_HMIR 0x141 // row_half_mirror     : lane ^ 7 (within 8-lane group)

template<int CTRL>
__device__ __forceinline__ float dppf(float v) {
    int i = __builtin_bit_cast(int, v);
    int r = __builtin_amdgcn_update_dpp(i, i, CTRL, 0xf, 0xf, false);
    return __builtin_bit_cast(float, r);
}

__device__ __forceinline__ float bperm(int byteaddr, float v) {
    int r = __builtin_amdgcn_ds_bpermute(byteaddr, __builtin_bit_cast(int, v));
    return __builtin_bit_cast(float, r);
}

__global__ __launch_bounds__(256, 2) void lstm_kernel(
    const float* __restrict__ x,    // (SEQ, BATCH, 2)
    const float* __restrict__ h0,   // (1, BATCH, 8)
    const float* __restrict__ c0,   // (1, BATCH, 8)
    const float* __restrict__ Wih,  // (32, 2)
    const float* __restrict__ Whh,  // (32, 8)
    const float* __restrict__ bih,  // (32)
    const float* __restrict__ bhh,  // (32)
    float* __restrict__ out)        // (1, BATCH, 8)
{
    const int tid = threadIdx.x;
    const int l32 = tid & 31;        // lane within 32-lane batch group
    const int g   = l32 >> 3;        // gate: 0=i 1=f 2=g~ 3=o
    const int u   = l32 & 7;         // unit 0..7
    const int b   = blockIdx.x * 8 + (tid >> 5);
    const int row = g * 8 + u;       // gate row in (32,·) weight matrices

    const float L2E = 1.4426950408889634f;
    const float cs  = -2.0f * L2E;
    // input scale folded into weights: sigmoid rows -L2E, tanh(g~) row -2*L2E
    const float smul = (g == 2) ? cs : -L2E;
    // finalize act = r*tm + addc per gate:
    //  i: tm=-2*L2E (emit -2L2E*sigma for scaled-c recurrence), addc=0
    //  f: tm=1       g~: tm=2, addc=-1 (tanh)       o: tm=2 (2*sigma)
    const float tm   = (g == 0) ? cs : ((g >= 2) ? 2.0f : 1.0f);
    const float addc = (g == 2) ? -1.0f : 0.0f;

    // Whh row in systolic visit order u^{0,1,3,2,5,4,6,7}, PRE-SCALED by smul
    const float* wr = Whh + row * 8;
    const float W0 = wr[u ^ 0] * smul, W1 = wr[u ^ 1] * smul;
    const float W2 = wr[u ^ 3] * smul, W3 = wr[u ^ 2] * smul;
    const float W4 = wr[u ^ 5] * smul, W5 = wr[u ^ 4] * smul;
    const float W6 = wr[u ^ 6] * smul, W7 = wr[u ^ 7] * smul;
    const float wx0 = Wih[2 * row] * smul, wx1 = Wih[2 * row + 1] * smul;
    const float bias = (bih[row] + bhh[row]) * smul;

    // ds_bpermute byte addresses of the 4 gate owners for this unit (per half)
    const int abase = ((tid & 32) | u) << 2;
    const int ai = abase, af = abase + 32, ag = abase + 64, ao = abase + 96;

    // state: c in scaled space c' = -2*L2E*c; h replicated in all 32 lanes
    float c = c0[b * 8 + u] * cs;
    float h = h0[b * 8 + u];

    const float2* __restrict__ xp2 = (const float2*)x;
    float2 xb[PF];
#pragma unroll
    for (int p = 0; p < PF; ++p) xb[p] = xp2[p * BATCH + b];

    for (int s = 0; s < SEQ; s += PF) {
#pragma unroll
        for (int p = 0; p < PF; ++p) {
            const float2 xc = xb[p];
            const int sn = (s + p + PF) & (SEQ - 1);   // uniform wrap
            xb[p] = xp2[sn * BATCH + b];

            // ---- systolic matvec: hr walks h_{u^0,1,3,2,5,4,6,7}; 2 fma chains
            float hr = h;
            float a0 = __builtin_fmaf(xc.x, wx0, bias);
            float a1 = xc.y * wx1;
            a0 = __builtin_fmaf(hr, W0, a0);
            hr = dppf<DPP_X1>(hr);   a1 = __builtin_fmaf(hr, W1, a1);
            hr = dppf<DPP_X2>(hr);   a0 = __builtin_fmaf(hr, W2, a0);
            hr = dppf<DPP_X1>(hr);   a1 = __builtin_fmaf(hr, W3, a1);
            hr = dppf<DPP_HMIR>(hr); a0 = __builtin_fmaf(hr, W4, a0);
            hr = dppf<DPP_X1>(hr);   a1 = __builtin_fmaf(hr, W5, a1);
            hr = dppf<DPP_X2>(hr);   a0 = __builtin_fmaf(hr, W6, a0);
            hr = dppf<DPP_X1>(hr);   a1 = __builtin_fmaf(hr, W7, a1);
            const float pre = a0 + a1;                 // already scaled

            // ---- activation: exp2 straight off the dot product
            const float e   = __builtin_amdgcn_exp2f(pre);
            const float r   = __builtin_amdgcn_rcpf(e + 1.0f);
            const float act = __builtin_fmaf(r, tm, addc);

            // ---- gate exchange on the DS pipe (uniform mapping via address)
            const float gi  = bperm(ai, act);   // -2L2E * sigma_i
            const float gf  = bperm(af, act);   // sigma_f
            const float gg  = bperm(ag, act);   // tanh(g~)
            const float go2 = bperm(ao, act);   // 2 * sigma_o

            // ---- c/h update, redundant in all lanes (h stays replicated)
            c = __builtin_fmaf(gf, c, gi * gg);        // scaled-c recurrence
            const float e2 = __builtin_amdgcn_exp2f(c);
            const float r2 = __builtin_amdgcn_rcpf(e2 + 1.0f);
            h = __builtin_fmaf(go2, r2, go2 * -0.5f);  // h = 2*sig_o*r2 - sig_o
        }
    }

    if (g == 0) out[b * 8 + u] = h;
}

extern "C" void kernel_launch(void* const* d_in, const int* in_sizes, int n_in,
                              void* d_out, int out_size, void* d_ws, size_t ws_size,
                              hipStream_t stream) {
    const float* x   = (const float*)d_in[0];
    const float* h0  = (const float*)d_in[1];
    const float* c0  = (const float*)d_in[2];
    const float* Wih = (const float*)d_in[3];
    const float* Whh = (const float*)d_in[4];
    const float* bih = (const float*)d_in[5];
    const float* bhh = (const float*)d_in[6];
    float* out = (float*)d_out;

    dim3 grid(BATCH / 8);    // 512 blocks -> 2 blocks/CU -> 2 waves/SIMD
    dim3 block(256);         // 8 batch groups of 32 lanes; 2048 waves total
    hipLaunchKernelGGL(lstm_kernel, grid, block, 0, stream,
                       x, h0, c0, Wih, Whh, bih, bhh, out);
}